// Round 6
// baseline (139.249 us; speedup 1.0000x reference)
//
#include <hip/hip_runtime.h>

// CREStereo grouped correlation, round 18.
// R17 post-mortem: native-left in corr was NET NEUTRAL (138.1 vs 138.6) --
// prepass's left_t round-trip was L3-absorbed (not HBM), so removing it
// saved nothing; corr inherited the 30.9MB cold left fetch + longer
// prologue (corr now 45.5us, no pipe >55%: latency/serialization-bound).
// R18: kill the meta-path scatter. 72 meta threads each issued 4 loads at
// stride-73728 addresses = ~288 lines (~18KB TD) per block, all on the
// pre-barrier critical path. Replace with cooperative staging: threads
// 0..159 load ONE float each (20 rows x 8 px, 32B contiguous per row,
// ~20-40 lines), park in LDS; meta threads compute from LDS (identical FP
// op order -> bit-identical). Left loads issued first. +1 barrier.
// Predict corr 45.5 -> 38-41, total -> ~133-135.

namespace {
constexpr int kB = 2;
constexpr int kC = 256;
constexpr int kH = 96;
constexpr int kW = 192;
constexpr int kG = 4;
constexpr int kGC = kC / kG;              // 64
constexpr int kK = 9;
constexpr int kHW = kH * kW;              // 18432
constexpr size_t kPlane = (size_t)kC * kHW;
constexpr int kTransBlocks = (kHW / 64) * (kC / 64) * kB;       // 2304 (right only)
constexpr int kCorrBlocks  = kB * kHW / 8;                      // 4608 (8 px/block)
}

typedef _Float16 half8_t __attribute__((ext_vector_type(8)));
typedef _Float16 half4_t __attribute__((ext_vector_type(4)));
typedef _Float16 half2_t __attribute__((ext_vector_type(2)));

struct TapMeta {        // 32 B: one (b,px,k) candidate
  int4   off;           // element offsets of 4 taps into right_t plane
  float4 wgt;           // bilinear weights (validity folded in)
};

__device__ __forceinline__ float dot8(half8_t a, half8_t b, float acc) {
#if __has_builtin(__builtin_amdgcn_fdot2)
  #pragma unroll
  for (int i = 0; i < 4; ++i) {
    half2_t a2 = {a[2 * i], a[2 * i + 1]};
    half2_t b2 = {b[2 * i], b[2 * i + 1]};
    acc = __builtin_amdgcn_fdot2(a2, b2, acc, false);
  }
#else
  #pragma unroll
  for (int i = 0; i < 8; ++i) acc += (float)a[i] * (float)b[i];
#endif
  return acc;
}

// ---- pre-pass: fp32->fp16 64x64 transpose of RIGHT only, 2304 blocks ----
__global__ __launch_bounds__(256) void prepass_kernel(
    const float* __restrict__ right, _Float16* __restrict__ right_t)
{
  __shared__ float tile[64][65];
  int tb = blockIdx.x;
  int pt = tb % (kHW / 64);         // pixel tile 0..287
  int ct = (tb / (kHW / 64)) % 4;   // channel tile 0..3
  int b  = tb / ((kHW / 64) * 4);   // batch
  int p0 = pt * 64, c0 = ct * 64;
  const float* inb = right + (size_t)b * kPlane;
  _Float16*   outb = right_t + (size_t)b * kPlane;
  int t = threadIdx.x;
  int cl = t >> 2;
  int q  = t & 3;
  #pragma unroll
  for (int i = 0; i < 4; ++i) {
    int j = q + 4 * i;
    float4 v = *(const float4*)(inb + (size_t)(c0 + cl) * kHW + p0 + 4 * j);
    tile[cl][4 * j + 0] = v.x;
    tile[cl][4 * j + 1] = v.y;
    tile[cl][4 * j + 2] = v.z;
    tile[cl][4 * j + 3] = v.w;
  }
  __syncthreads();
  int pl8 = t >> 3;                 // pixel 0..31 (+32*i)
  int c8  = t & 7;                  // channel octet
  #pragma unroll
  for (int i = 0; i < 2; ++i) {
    int px = pl8 + 32 * i;
    half8_t hv;
    #pragma unroll
    for (int j = 0; j < 8; ++j)
      hv[j] = (_Float16)tile[8 * c8 + j][px];
    *(half8_t*)(outb + (size_t)(p0 + px) * kC + c0 + 8 * c8) = hv;
  }
}

// ---- main: block = 8 px; wave = 2 px x 32 lanes; lane owns 8 ch ----
// R18: flow/extra cooperatively staged (1 float/thread) -> LDS; meta math
// reads LDS. Left gathered natively; TapMeta inline; XCD swizzle.
__global__ __launch_bounds__(256) void corr_fp16_kernel(
    const _Float16* __restrict__ right_t, const float* __restrict__ left,
    const float* __restrict__ flow, const float* __restrict__ extra,
    float* __restrict__ out)
{
  __shared__ TapMeta smeta[8 * kK];         // 2304 B
  __shared__ _Float16 smleft[8][kC];        // 4 KB
  __shared__ float smflow[20][8];           // 640 B: rows 0-1 flow, 2-19 extra

  // XCD-chunked swizzle: 4608 blocks -> XCD i owns blocks [i*576,(i+1)*576).
  int sb = (blockIdx.x & 7) * (kCorrBlocks / 8) + (blockIdx.x >> 3);
  int blockPix = sb * 8;                // first of 8 pixels (global, b-major)
  int b    = blockPix / kHW;            // blocks never straddle batch
  int pix0 = blockPix % kHW;            // 8-aligned; W%8==0 -> same image row

  int t = threadIdx.x;

  // (1) issue left gather first: thread t = channel t, 8 px = 32 B.
  const float* Lb = left + (size_t)b * kPlane + (size_t)t * kHW + pix0;
  float4 lv0 = *(const float4*)(Lb);
  float4 lv1 = *(const float4*)(Lb + 4);

  // (2) cooperative flow/extra stage: t<160 loads exactly one float.
  //     row r<2: flow[b][r][pix0+px]; row r>=2: extra[b][r-2][pix0+px].
  float fval = 0.f;
  int fr = t >> 3, fpx = t & 7;
  if (t < 160) {
    const float* src = (fr < 2)
        ? flow  + ((size_t)b * 2  + fr)       * kHW + pix0 + fpx
        : extra + ((size_t)b * 18 + (fr - 2)) * kHW + pix0 + fpx;
    fval = *src;
  }

  // (3) LDS parks
  if (t < 160) smflow[fr][fpx] = fval;
  {
    float lv[8] = {lv0.x, lv0.y, lv0.z, lv0.w, lv1.x, lv1.y, lv1.z, lv1.w};
    #pragma unroll
    for (int j = 0; j < 8; ++j)
      smleft[j][t] = (_Float16)lv[j];
  }
  __syncthreads();

  // (4) meta math from LDS: t<72 computes TapMeta for (px=t/9, k=t%9).
  if (t < 8 * kK) {
    int px = t / kK;
    int k  = t - px * kK;
    int gpix = pix0 + px;
    int w = gpix % kW, h = gpix / kW;

    float bx = (float)w + smflow[0][px];
    float by = (float)h + smflow[1][px];
    float xx = bx + (float)(k - 4) + smflow[2 + 2 * k][px];
    float yy = by + smflow[2 + 2 * k + 1][px];
    float xf = floorf(xx), yf = floorf(yy);
    float fx = xx - xf, fy = yy - yf;
    int ix0 = (int)xf, iy0 = (int)yf;
    int ix1 = ix0 + 1, iy1 = iy0 + 1;
    bool vx0 = (ix0 >= 0) && (ix0 < kW);
    bool vx1 = (ix1 >= 0) && (ix1 < kW);
    bool vy0 = (iy0 >= 0) && (iy0 < kH);
    bool vy1 = (iy1 >= 0) && (iy1 < kH);
    int xc0 = min(max(ix0, 0), kW - 1);
    int xc1 = min(max(ix1, 0), kW - 1);
    int yc0 = min(max(iy0, 0), kH - 1);
    int yc1 = min(max(iy1, 0), kH - 1);
    float wx0 = 1.f - fx, wy0 = 1.f - fy;
    TapMeta m;
    m.off.x = (yc0 * kW + xc0) * kC;
    m.off.y = (yc0 * kW + xc1) * kC;
    m.off.z = (yc1 * kW + xc0) * kC;
    m.off.w = (yc1 * kW + xc1) * kC;
    m.wgt.x = wx0 * wy0 * ((vx0 && vy0) ? 1.f : 0.f);
    m.wgt.y = fx  * wy0 * ((vx1 && vy0) ? 1.f : 0.f);
    m.wgt.z = wx0 * fy  * ((vx0 && vy1) ? 1.f : 0.f);
    m.wgt.w = fx  * fy  * ((vx1 && vy1) ? 1.f : 0.f);
    smeta[t] = m;
  }

  int wv   = t >> 6;                    // wave in block 0..3
  int lane = t & 63;
  int p    = lane >> 5;                 // pixel cluster 0..1
  int cl   = lane & 31;                 // channel-lane: owns channels cl*8..cl*8+7
  int pix  = pix0 + wv * 2 + p;

  const _Float16* Rb = right_t + (size_t)b * kPlane + cl * 8;

  __syncthreads();

  half8_t l8 = *(const half8_t*)&smleft[wv * 2 + p][cl * 8];
  const TapMeta* mp = smeta + (wv * 2 + p) * kK;   // LDS, broadcast reads

  float rr[kK];

  #pragma unroll
  for (int kb = 0; kb < kK; kb += 3) {
    int4   off[3];
    float4 wv4[3];
    #pragma unroll
    for (int j = 0; j < 3; ++j) {
      off[j] = mp[kb + j].off;
      wv4[j] = mp[kb + j].wgt;
    }
    half8_t tp[3][4];
    #pragma unroll
    for (int j = 0; j < 3; ++j) {
      tp[j][0] = *(const half8_t*)(Rb + off[j].x);
      tp[j][1] = *(const half8_t*)(Rb + off[j].y);
      tp[j][2] = *(const half8_t*)(Rb + off[j].z);
      tp[j][3] = *(const half8_t*)(Rb + off[j].w);
    }
    #pragma unroll
    for (int j = 0; j < 3; ++j) {
      float d00 = dot8(tp[j][0], l8, 0.f);
      float d01 = dot8(tp[j][1], l8, 0.f);
      float d10 = dot8(tp[j][2], l8, 0.f);
      float d11 = dot8(tp[j][3], l8, 0.f);
      float r = wv4[j].x * d00 + wv4[j].y * d01 + wv4[j].z * d10 + wv4[j].w * d11;
      r += __shfl_xor(r, 1);
      r += __shfl_xor(r, 2);
      r += __shfl_xor(r, 4);
      rr[kb + j] = r;           // all lanes hold the group sum
    }
  }

  // single masked store block: exec mask changes once
  int g = cl >> 3;
  if ((cl & 7) == 0) {
    float* outp = out + ((size_t)b * kG + g) * kK * kHW + pix;
    #pragma unroll
    for (int k = 0; k < kK; ++k)
      outp[(size_t)k * kHW] = rr[k] * (1.f / kGC);
  }
}

// ---- fallback (round-2 kernel) if workspace too small ----
__global__ __launch_bounds__(256) void crestereo_corr_fallback(
    const float* __restrict__ left, const float* __restrict__ right,
    const float* __restrict__ flow, const float* __restrict__ extra,
    float* __restrict__ out)
{
  int t = blockIdx.x * blockDim.x + threadIdx.x;
  int w = t % kW;
  int h = (t / kW) % kH;
  int k = (t / kHW) % kK;
  int g = (t / (kHW * kK)) % kG;
  int b = t / (kHW * kK * kG);

  int pix = h * kW + w;
  const float* flowb = flow + b * 2 * kHW + pix;
  float x = (float)(w + (k - 4)) + flowb[0];
  float y = (float)h + flowb[kHW];
  const float* extb = extra + (size_t)(b * 2 * kK + 2 * k) * kHW + pix;
  x += extb[0];
  y += extb[kHW];

  float xf = floorf(x), yf = floorf(y);
  float fx = x - xf, fy = y - yf;
  int ix0 = (int)xf, iy0 = (int)yf;
  int ix1 = ix0 + 1, iy1 = iy0 + 1;
  bool vx0 = (ix0 >= 0) && (ix0 < kW);
  bool vx1 = (ix1 >= 0) && (ix1 < kW);
  bool vy0 = (iy0 >= 0) && (iy0 < kH);
  bool vy1 = (iy1 >= 0) && (iy1 < kH);
  int xc0 = min(max(ix0, 0), kW - 1);
  int xc1 = min(max(ix1, 0), kW - 1);
  int yc0 = min(max(iy0, 0), kH - 1);
  int yc1 = min(max(iy1, 0), kH - 1);
  float wx0 = 1.f - fx, wy0 = 1.f - fy;
  float w00 = wx0 * wy0 * ((vx0 && vy0) ? 1.f : 0.f);
  float w01 = fx  * wy0 * ((vx1 && vy0) ? 1.f : 0.f);
  float w10 = wx0 * fy  * ((vx0 && vy1) ? 1.f : 0.f);
  float w11 = fx  * fy  * ((vx1 && vy1) ? 1.f : 0.f);
  int idx = yc0 * kW + xc0;
  int dx  = xc1 - xc0;
  int dyw = (yc1 - yc0) * kW;

  const float* Rb = right + (size_t)(b * kC + g * kGC) * kHW + idx;
  const float* Lb = left  + (size_t)(b * kC + g * kGC) * kHW + pix;

  float acc = 0.f;
  #pragma unroll 4
  for (int c = 0; c < kGC; ++c) {
    const float* Rc = Rb + (size_t)c * kHW;
    float l   = Lb[(size_t)c * kHW];
    acc += l * (w00 * Rc[0] + w01 * Rc[dx] + w10 * Rc[dyw] + w11 * Rc[dx + dyw]);
  }
  out[(size_t)((b * kG + g) * kK + k) * kHW + pix] = acc * (1.f / kGC);
}

extern "C" void kernel_launch(void* const* d_in, const int* in_sizes, int n_in,
                              void* d_out, int out_size, void* d_ws, size_t ws_size,
                              hipStream_t stream) {
  const float* left  = (const float*)d_in[0];
  const float* right = (const float*)d_in[1];
  const float* flow  = (const float*)d_in[2];
  const float* extra = (const float*)d_in[3];
  float* out = (float*)d_out;

  size_t t_bytes = (size_t)kB * kPlane * sizeof(_Float16);   // 18.9 MB (right_t)
  if (ws_size >= t_bytes) {
    _Float16* right_t = (_Float16*)d_ws;

    prepass_kernel<<<kTransBlocks, 256, 0, stream>>>(right, right_t);
    corr_fp16_kernel<<<kCorrBlocks, 256, 0, stream>>>(
        right_t, left, flow, extra, out);
  } else {
    int total = kB * kG * kK * kH * kW;
    crestereo_corr_fallback<<<(total + 255) / 256, 256, 0, stream>>>(
        left, right, flow, extra, out);
  }
}

// Round 7
// 139.212 us; speedup vs baseline: 1.0003x; 1.0003x over previous
//
#include <hip/hip_runtime.h>

// CREStereo grouped correlation, round 19.
// R18 post-mortem: meta-scatter staging NEUTRAL (corr still 45.5us). Two
// byte-reduction attempts neutral => corr NOT byte-bound. Counters show no
// saturated pipe (HBM 10%, VALU 27%, occ 58%) = LATENCY-bound. Smoking gun:
// VGPR_Count=36 -- one 12-tap batch needs 48 VGPRs of destinations, so the
// compiler was issuing loads in ~4-load dribbles with waits between,
// exposing ~250cy L2 latency ~9x per k-loop. Default launch_bounds(256)
// optimized for 8 waves/SIMD we never use (only 18 blocks/CU exist).
// R19: __launch_bounds__(256,4) (VGPR cap 128) + explicit double-buffered
// tap pipeline: LOAD(A,0);LOAD(B,3);COMP(A,0);LOAD(A,6);COMP(B,3);COMP(A,6)
// -- 24 taps (96 VGPR) in flight, 1-2 latency exposures instead of 9.
// Weights read lazily from LDS (lgkmcnt path, off vmcnt).
// Predict VGPR ~110-128, corr 45.5 -> 33-38, total ~128-133.

namespace {
constexpr int kB = 2;
constexpr int kC = 256;
constexpr int kH = 96;
constexpr int kW = 192;
constexpr int kG = 4;
constexpr int kGC = kC / kG;              // 64
constexpr int kK = 9;
constexpr int kHW = kH * kW;              // 18432
constexpr size_t kPlane = (size_t)kC * kHW;
constexpr int kTransBlocks = (kHW / 64) * (kC / 64) * kB;       // 2304 (right only)
constexpr int kCorrBlocks  = kB * kHW / 8;                      // 4608 (8 px/block)
}

typedef _Float16 half8_t __attribute__((ext_vector_type(8)));
typedef _Float16 half2_t __attribute__((ext_vector_type(2)));

struct TapMeta {        // 32 B: one (b,px,k) candidate
  int4   off;           // element offsets of 4 taps into right_t plane
  float4 wgt;           // bilinear weights (validity folded in)
};

__device__ __forceinline__ float dot8(half8_t a, half8_t b, float acc) {
#if __has_builtin(__builtin_amdgcn_fdot2)
  #pragma unroll
  for (int i = 0; i < 4; ++i) {
    half2_t a2 = {a[2 * i], a[2 * i + 1]};
    half2_t b2 = {b[2 * i], b[2 * i + 1]};
    acc = __builtin_amdgcn_fdot2(a2, b2, acc, false);
  }
#else
  #pragma unroll
  for (int i = 0; i < 8; ++i) acc += (float)a[i] * (float)b[i];
#endif
  return acc;
}

// ---- pre-pass: fp32->fp16 64x64 transpose of RIGHT only, 2304 blocks ----
__global__ __launch_bounds__(256) void prepass_kernel(
    const float* __restrict__ right, _Float16* __restrict__ right_t)
{
  __shared__ float tile[64][65];
  int tb = blockIdx.x;
  int pt = tb % (kHW / 64);         // pixel tile 0..287
  int ct = (tb / (kHW / 64)) % 4;   // channel tile 0..3
  int b  = tb / ((kHW / 64) * 4);   // batch
  int p0 = pt * 64, c0 = ct * 64;
  const float* inb = right + (size_t)b * kPlane;
  _Float16*   outb = right_t + (size_t)b * kPlane;
  int t = threadIdx.x;
  int cl = t >> 2;
  int q  = t & 3;
  #pragma unroll
  for (int i = 0; i < 4; ++i) {
    int j = q + 4 * i;
    float4 v = *(const float4*)(inb + (size_t)(c0 + cl) * kHW + p0 + 4 * j);
    tile[cl][4 * j + 0] = v.x;
    tile[cl][4 * j + 1] = v.y;
    tile[cl][4 * j + 2] = v.z;
    tile[cl][4 * j + 3] = v.w;
  }
  __syncthreads();
  int pl8 = t >> 3;                 // pixel 0..31 (+32*i)
  int c8  = t & 7;                  // channel octet
  #pragma unroll
  for (int i = 0; i < 2; ++i) {
    int px = pl8 + 32 * i;
    half8_t hv;
    #pragma unroll
    for (int j = 0; j < 8; ++j)
      hv[j] = (_Float16)tile[8 * c8 + j][px];
    *(half8_t*)(outb + (size_t)(p0 + px) * kC + c0 + 8 * c8) = hv;
  }
}

// ---- main: block = 8 px; wave = 2 px x 32 lanes; lane owns 8 ch ----
// R19: double-buffered 12-tap register pipeline, launch_bounds(256,4).
__global__ __launch_bounds__(256, 4) void corr_fp16_kernel(
    const _Float16* __restrict__ right_t, const float* __restrict__ left,
    const float* __restrict__ flow, const float* __restrict__ extra,
    float* __restrict__ out)
{
  __shared__ TapMeta smeta[8 * kK];         // 2304 B
  __shared__ _Float16 smleft[8][kC];        // 4 KB
  __shared__ float smflow[20][8];           // 640 B: rows 0-1 flow, 2-19 extra

  // XCD-chunked swizzle: 4608 blocks -> XCD i owns blocks [i*576,(i+1)*576).
  int sb = (blockIdx.x & 7) * (kCorrBlocks / 8) + (blockIdx.x >> 3);
  int blockPix = sb * 8;                // first of 8 pixels (global, b-major)
  int b    = blockPix / kHW;            // blocks never straddle batch
  int pix0 = blockPix % kHW;            // 8-aligned; W%8==0 -> same image row

  int t = threadIdx.x;

  // (1) issue left gather first: thread t = channel t, 8 px = 32 B.
  const float* Lb = left + (size_t)b * kPlane + (size_t)t * kHW + pix0;
  float4 lv0 = *(const float4*)(Lb);
  float4 lv1 = *(const float4*)(Lb + 4);

  // (2) cooperative flow/extra stage: t<160 loads exactly one float.
  float fval = 0.f;
  int fr = t >> 3, fpx = t & 7;
  if (t < 160) {
    const float* src = (fr < 2)
        ? flow  + ((size_t)b * 2  + fr)       * kHW + pix0 + fpx
        : extra + ((size_t)b * 18 + (fr - 2)) * kHW + pix0 + fpx;
    fval = *src;
  }

  // (3) LDS parks
  if (t < 160) smflow[fr][fpx] = fval;
  {
    float lv[8] = {lv0.x, lv0.y, lv0.z, lv0.w, lv1.x, lv1.y, lv1.z, lv1.w};
    #pragma unroll
    for (int j = 0; j < 8; ++j)
      smleft[j][t] = (_Float16)lv[j];
  }
  __syncthreads();

  // (4) meta math from LDS: t<72 computes TapMeta for (px=t/9, k=t%9).
  if (t < 8 * kK) {
    int px = t / kK;
    int k  = t - px * kK;
    int gpix = pix0 + px;
    int w = gpix % kW, h = gpix / kW;

    float bx = (float)w + smflow[0][px];
    float by = (float)h + smflow[1][px];
    float xx = bx + (float)(k - 4) + smflow[2 + 2 * k][px];
    float yy = by + smflow[2 + 2 * k + 1][px];
    float xf = floorf(xx), yf = floorf(yy);
    float fx = xx - xf, fy = yy - yf;
    int ix0 = (int)xf, iy0 = (int)yf;
    int ix1 = ix0 + 1, iy1 = iy0 + 1;
    bool vx0 = (ix0 >= 0) && (ix0 < kW);
    bool vx1 = (ix1 >= 0) && (ix1 < kW);
    bool vy0 = (iy0 >= 0) && (iy0 < kH);
    bool vy1 = (iy1 >= 0) && (iy1 < kH);
    int xc0 = min(max(ix0, 0), kW - 1);
    int xc1 = min(max(ix1, 0), kW - 1);
    int yc0 = min(max(iy0, 0), kH - 1);
    int yc1 = min(max(iy1, 0), kH - 1);
    float wx0 = 1.f - fx, wy0 = 1.f - fy;
    TapMeta m;
    m.off.x = (yc0 * kW + xc0) * kC;
    m.off.y = (yc0 * kW + xc1) * kC;
    m.off.z = (yc1 * kW + xc0) * kC;
    m.off.w = (yc1 * kW + xc1) * kC;
    m.wgt.x = wx0 * wy0 * ((vx0 && vy0) ? 1.f : 0.f);
    m.wgt.y = fx  * wy0 * ((vx1 && vy0) ? 1.f : 0.f);
    m.wgt.z = wx0 * fy  * ((vx0 && vy1) ? 1.f : 0.f);
    m.wgt.w = fx  * fy  * ((vx1 && vy1) ? 1.f : 0.f);
    smeta[t] = m;
  }

  int wv   = t >> 6;                    // wave in block 0..3
  int lane = t & 63;
  int p    = lane >> 5;                 // pixel cluster 0..1
  int cl   = lane & 31;                 // channel-lane: owns channels cl*8..cl*8+7
  int pix  = pix0 + wv * 2 + p;

  const _Float16* Rb = right_t + (size_t)b * kPlane + cl * 8;

  __syncthreads();

  half8_t l8 = *(const half8_t*)&smleft[wv * 2 + p][cl * 8];
  const TapMeta* mp = smeta + (wv * 2 + p) * kK;   // LDS, broadcast reads

  float rr[kK];
  half8_t tA[12], tB[12];

  // load 12 taps for k-batch KB into register slot T (vmcnt path only)
#define LOAD_TAPS(T, KB) do {                                      \
    int4 o0 = mp[(KB)].off, o1 = mp[(KB) + 1].off, o2 = mp[(KB) + 2].off; \
    T[0]  = *(const half8_t*)(Rb + o0.x);                          \
    T[1]  = *(const half8_t*)(Rb + o0.y);                          \
    T[2]  = *(const half8_t*)(Rb + o0.z);                          \
    T[3]  = *(const half8_t*)(Rb + o0.w);                          \
    T[4]  = *(const half8_t*)(Rb + o1.x);                          \
    T[5]  = *(const half8_t*)(Rb + o1.y);                          \
    T[6]  = *(const half8_t*)(Rb + o1.z);                          \
    T[7]  = *(const half8_t*)(Rb + o1.w);                          \
    T[8]  = *(const half8_t*)(Rb + o2.x);                          \
    T[9]  = *(const half8_t*)(Rb + o2.y);                          \
    T[10] = *(const half8_t*)(Rb + o2.z);                          \
    T[11] = *(const half8_t*)(Rb + o2.w);                          \
  } while (0)

  // weights read lazily from LDS at compute time (off the vmcnt path)
#define COMP_TAPS(T, KB) do {                                      \
    _Pragma("unroll")                                              \
    for (int j = 0; j < 3; ++j) {                                  \
      float4 w4 = mp[(KB) + j].wgt;                                \
      float d00 = dot8(T[4 * j + 0], l8, 0.f);                     \
      float d01 = dot8(T[4 * j + 1], l8, 0.f);                     \
      float d10 = dot8(T[4 * j + 2], l8, 0.f);                     \
      float d11 = dot8(T[4 * j + 3], l8, 0.f);                     \
      float r = w4.x * d00 + w4.y * d01 + w4.z * d10 + w4.w * d11; \
      r += __shfl_xor(r, 1);                                       \
      r += __shfl_xor(r, 2);                                       \
      r += __shfl_xor(r, 4);                                       \
      rr[(KB) + j] = r;                                            \
    }                                                              \
  } while (0)

  LOAD_TAPS(tA, 0);
  LOAD_TAPS(tB, 3);
  COMP_TAPS(tA, 0);
  LOAD_TAPS(tA, 6);
  COMP_TAPS(tB, 3);
  COMP_TAPS(tA, 6);

#undef LOAD_TAPS
#undef COMP_TAPS

  // single masked store block: exec mask changes once
  int g = cl >> 3;
  if ((cl & 7) == 0) {
    float* outp = out + ((size_t)b * kG + g) * kK * kHW + pix;
    #pragma unroll
    for (int k = 0; k < kK; ++k)
      outp[(size_t)k * kHW] = rr[k] * (1.f / kGC);
  }
}

// ---- fallback (round-2 kernel) if workspace too small ----
__global__ __launch_bounds__(256) void crestereo_corr_fallback(
    const float* __restrict__ left, const float* __restrict__ right,
    const float* __restrict__ flow, const float* __restrict__ extra,
    float* __restrict__ out)
{
  int t = blockIdx.x * blockDim.x + threadIdx.x;
  int w = t % kW;
  int h = (t / kW) % kH;
  int k = (t / kHW) % kK;
  int g = (t / (kHW * kK)) % kG;
  int b = t / (kHW * kK * kG);

  int pix = h * kW + w;
  const float* flowb = flow + b * 2 * kHW + pix;
  float x = (float)(w + (k - 4)) + flowb[0];
  float y = (float)h + flowb[kHW];
  const float* extb = extra + (size_t)(b * 2 * kK + 2 * k) * kHW + pix;
  x += extb[0];
  y += extb[kHW];

  float xf = floorf(x), yf = floorf(y);
  float fx = x - xf, fy = y - yf;
  int ix0 = (int)xf, iy0 = (int)yf;
  int ix1 = ix0 + 1, iy1 = iy0 + 1;
  bool vx0 = (ix0 >= 0) && (ix0 < kW);
  bool vx1 = (ix1 >= 0) && (ix1 < kW);
  bool vy0 = (iy0 >= 0) && (iy0 < kH);
  bool vy1 = (iy1 >= 0) && (iy1 < kH);
  int xc0 = min(max(ix0, 0), kW - 1);
  int xc1 = min(max(ix1, 0), kW - 1);
  int yc0 = min(max(iy0, 0), kH - 1);
  int yc1 = min(max(iy1, 0), kH - 1);
  float wx0 = 1.f - fx, wy0 = 1.f - fy;
  float w00 = wx0 * wy0 * ((vx0 && vy0) ? 1.f : 0.f);
  float w01 = fx  * wy0 * ((vx1 && vy0) ? 1.f : 0.f);
  float w10 = wx0 * fy  * ((vx0 && vy1) ? 1.f : 0.f);
  float w11 = fx  * fy  * ((vx1 && vy1) ? 1.f : 0.f);
  int idx = yc0 * kW + xc0;
  int dx  = xc1 - xc0;
  int dyw = (yc1 - yc0) * kW;

  const float* Rb = right + (size_t)(b * kC + g * kGC) * kHW + idx;
  const float* Lb = left  + (size_t)(b * kC + g * kGC) * kHW + pix;

  float acc = 0.f;
  #pragma unroll 4
  for (int c = 0; c < kGC; ++c) {
    const float* Rc = Rb + (size_t)c * kHW;
    float l   = Lb[(size_t)c * kHW];
    acc += l * (w00 * Rc[0] + w01 * Rc[dx] + w10 * Rc[dyw] + w11 * Rc[dx + dyw]);
  }
  out[(size_t)((b * kG + g) * kK + k) * kHW + pix] = acc * (1.f / kGC);
}

extern "C" void kernel_launch(void* const* d_in, const int* in_sizes, int n_in,
                              void* d_out, int out_size, void* d_ws, size_t ws_size,
                              hipStream_t stream) {
  const float* left  = (const float*)d_in[0];
  const float* right = (const float*)d_in[1];
  const float* flow  = (const float*)d_in[2];
  const float* extra = (const float*)d_in[3];
  float* out = (float*)d_out;

  size_t t_bytes = (size_t)kB * kPlane * sizeof(_Float16);   // 18.9 MB (right_t)
  if (ws_size >= t_bytes) {
    _Float16* right_t = (_Float16*)d_ws;

    prepass_kernel<<<kTransBlocks, 256, 0, stream>>>(right, right_t);
    corr_fp16_kernel<<<kCorrBlocks, 256, 0, stream>>>(
        right_t, left, flow, extra, out);
  } else {
    int total = kB * kG * kK * kH * kW;
    crestereo_corr_fallback<<<(total + 255) / 256, 256, 0, stream>>>(
        left, right, flow, extra, out);
  }
}

// Round 8
// 136.872 us; speedup vs baseline: 1.0174x; 1.0171x over previous
//
#include <hip/hip_runtime.h>

// CREStereo grouped correlation, round 20.
// R19 post-mortem: compiler DISCARDED the source-level double-buffer --
// VGPR_Count 36->32 (predicted 110+). With no fence, the scheduler
// re-interleaved load->use to minimize pressure, keeping ~2-3 loads in
// flight and the same ~12 exposed L2 waits/wave. corr frozen at 45.5us.
// Latency-bound diagnosis stands; the mechanism failed.
// R20: pin the schedule with __builtin_amdgcn_sched_barrier(0) fences:
//   LOAD(A,0) LOAD(B,3) |SB| COMP(A,0) LOAD(A,6) |SB| COMP(B,3) COMP(A,6)
// 24 taps live across fence 1 => allocator must hold 96 VGPR of dests;
// waits collapse to 3 (vmcnt(12)/12/0), each 12-deep. launch_bounds(256,3)
// (~168 VGPR budget) to avoid spill; occupancy ~37% acceptable since waves
// now self-hide latency.
// VERIFY: VGPR_Count must jump to ~110-160. If still ~32 -> inline asm next.
// Predict corr 45.5 -> 27-35, total -> 122-130. absmax bit-identical.

namespace {
constexpr int kB = 2;
constexpr int kC = 256;
constexpr int kH = 96;
constexpr int kW = 192;
constexpr int kG = 4;
constexpr int kGC = kC / kG;              // 64
constexpr int kK = 9;
constexpr int kHW = kH * kW;              // 18432
constexpr size_t kPlane = (size_t)kC * kHW;
constexpr int kTransBlocks = (kHW / 64) * (kC / 64) * kB;       // 2304 (right only)
constexpr int kCorrBlocks  = kB * kHW / 8;                      // 4608 (8 px/block)
}

typedef _Float16 half8_t __attribute__((ext_vector_type(8)));
typedef _Float16 half2_t __attribute__((ext_vector_type(2)));

struct TapMeta {        // 32 B: one (b,px,k) candidate
  int4   off;           // element offsets of 4 taps into right_t plane
  float4 wgt;           // bilinear weights (validity folded in)
};

__device__ __forceinline__ float dot8(half8_t a, half8_t b, float acc) {
#if __has_builtin(__builtin_amdgcn_fdot2)
  #pragma unroll
  for (int i = 0; i < 4; ++i) {
    half2_t a2 = {a[2 * i], a[2 * i + 1]};
    half2_t b2 = {b[2 * i], b[2 * i + 1]};
    acc = __builtin_amdgcn_fdot2(a2, b2, acc, false);
  }
#else
  #pragma unroll
  for (int i = 0; i < 8; ++i) acc += (float)a[i] * (float)b[i];
#endif
  return acc;
}

// ---- pre-pass: fp32->fp16 64x64 transpose of RIGHT only, 2304 blocks ----
__global__ __launch_bounds__(256) void prepass_kernel(
    const float* __restrict__ right, _Float16* __restrict__ right_t)
{
  __shared__ float tile[64][65];
  int tb = blockIdx.x;
  int pt = tb % (kHW / 64);         // pixel tile 0..287
  int ct = (tb / (kHW / 64)) % 4;   // channel tile 0..3
  int b  = tb / ((kHW / 64) * 4);   // batch
  int p0 = pt * 64, c0 = ct * 64;
  const float* inb = right + (size_t)b * kPlane;
  _Float16*   outb = right_t + (size_t)b * kPlane;
  int t = threadIdx.x;
  int cl = t >> 2;
  int q  = t & 3;
  #pragma unroll
  for (int i = 0; i < 4; ++i) {
    int j = q + 4 * i;
    float4 v = *(const float4*)(inb + (size_t)(c0 + cl) * kHW + p0 + 4 * j);
    tile[cl][4 * j + 0] = v.x;
    tile[cl][4 * j + 1] = v.y;
    tile[cl][4 * j + 2] = v.z;
    tile[cl][4 * j + 3] = v.w;
  }
  __syncthreads();
  int pl8 = t >> 3;                 // pixel 0..31 (+32*i)
  int c8  = t & 7;                  // channel octet
  #pragma unroll
  for (int i = 0; i < 2; ++i) {
    int px = pl8 + 32 * i;
    half8_t hv;
    #pragma unroll
    for (int j = 0; j < 8; ++j)
      hv[j] = (_Float16)tile[8 * c8 + j][px];
    *(half8_t*)(outb + (size_t)(p0 + px) * kC + c0 + 8 * c8) = hv;
  }
}

// ---- main: block = 8 px; wave = 2 px x 32 lanes; lane owns 8 ch ----
// R20: sched_barrier-pinned 24-tap-deep load pipeline, launch_bounds(256,3).
__global__ __launch_bounds__(256, 3) void corr_fp16_kernel(
    const _Float16* __restrict__ right_t, const float* __restrict__ left,
    const float* __restrict__ flow, const float* __restrict__ extra,
    float* __restrict__ out)
{
  __shared__ TapMeta smeta[8 * kK];         // 2304 B
  __shared__ _Float16 smleft[8][kC];        // 4 KB
  __shared__ float smflow[20][8];           // 640 B: rows 0-1 flow, 2-19 extra

  // XCD-chunked swizzle: 4608 blocks -> XCD i owns blocks [i*576,(i+1)*576).
  int sb = (blockIdx.x & 7) * (kCorrBlocks / 8) + (blockIdx.x >> 3);
  int blockPix = sb * 8;                // first of 8 pixels (global, b-major)
  int b    = blockPix / kHW;            // blocks never straddle batch
  int pix0 = blockPix % kHW;            // 8-aligned; W%8==0 -> same image row

  int t = threadIdx.x;

  // (1) issue left gather first: thread t = channel t, 8 px = 32 B.
  const float* Lb = left + (size_t)b * kPlane + (size_t)t * kHW + pix0;
  float4 lv0 = *(const float4*)(Lb);
  float4 lv1 = *(const float4*)(Lb + 4);

  // (2) cooperative flow/extra stage: t<160 loads exactly one float.
  float fval = 0.f;
  int fr = t >> 3, fpx = t & 7;
  if (t < 160) {
    const float* src = (fr < 2)
        ? flow  + ((size_t)b * 2  + fr)       * kHW + pix0 + fpx
        : extra + ((size_t)b * 18 + (fr - 2)) * kHW + pix0 + fpx;
    fval = *src;
  }

  // (3) LDS parks
  if (t < 160) smflow[fr][fpx] = fval;
  {
    float lv[8] = {lv0.x, lv0.y, lv0.z, lv0.w, lv1.x, lv1.y, lv1.z, lv1.w};
    #pragma unroll
    for (int j = 0; j < 8; ++j)
      smleft[j][t] = (_Float16)lv[j];
  }
  __syncthreads();

  // (4) meta math from LDS: t<72 computes TapMeta for (px=t/9, k=t%9).
  if (t < 8 * kK) {
    int px = t / kK;
    int k  = t - px * kK;
    int gpix = pix0 + px;
    int w = gpix % kW, h = gpix / kW;

    float bx = (float)w + smflow[0][px];
    float by = (float)h + smflow[1][px];
    float xx = bx + (float)(k - 4) + smflow[2 + 2 * k][px];
    float yy = by + smflow[2 + 2 * k + 1][px];
    float xf = floorf(xx), yf = floorf(yy);
    float fx = xx - xf, fy = yy - yf;
    int ix0 = (int)xf, iy0 = (int)yf;
    int ix1 = ix0 + 1, iy1 = iy0 + 1;
    bool vx0 = (ix0 >= 0) && (ix0 < kW);
    bool vx1 = (ix1 >= 0) && (ix1 < kW);
    bool vy0 = (iy0 >= 0) && (iy0 < kH);
    bool vy1 = (iy1 >= 0) && (iy1 < kH);
    int xc0 = min(max(ix0, 0), kW - 1);
    int xc1 = min(max(ix1, 0), kW - 1);
    int yc0 = min(max(iy0, 0), kH - 1);
    int yc1 = min(max(iy1, 0), kH - 1);
    float wx0 = 1.f - fx, wy0 = 1.f - fy;
    TapMeta m;
    m.off.x = (yc0 * kW + xc0) * kC;
    m.off.y = (yc0 * kW + xc1) * kC;
    m.off.z = (yc1 * kW + xc0) * kC;
    m.off.w = (yc1 * kW + xc1) * kC;
    m.wgt.x = wx0 * wy0 * ((vx0 && vy0) ? 1.f : 0.f);
    m.wgt.y = fx  * wy0 * ((vx1 && vy0) ? 1.f : 0.f);
    m.wgt.z = wx0 * fy  * ((vx0 && vy1) ? 1.f : 0.f);
    m.wgt.w = fx  * fy  * ((vx1 && vy1) ? 1.f : 0.f);
    smeta[t] = m;
  }

  int wv   = t >> 6;                    // wave in block 0..3
  int lane = t & 63;
  int p    = lane >> 5;                 // pixel cluster 0..1
  int cl   = lane & 31;                 // channel-lane: owns channels cl*8..cl*8+7
  int pix  = pix0 + wv * 2 + p;

  const _Float16* Rb = right_t + (size_t)b * kPlane + cl * 8;

  __syncthreads();

  half8_t l8 = *(const half8_t*)&smleft[wv * 2 + p][cl * 8];
  const TapMeta* mp = smeta + (wv * 2 + p) * kK;   // LDS, broadcast reads

  float rr[kK];
  half8_t tA[12], tB[12];

#define LOAD_TAPS(T, KB) do {                                      \
    int4 o0 = mp[(KB)].off, o1 = mp[(KB) + 1].off, o2 = mp[(KB) + 2].off; \
    T[0]  = *(const half8_t*)(Rb + o0.x);                          \
    T[1]  = *(const half8_t*)(Rb + o0.y);                          \
    T[2]  = *(const half8_t*)(Rb + o0.z);                          \
    T[3]  = *(const half8_t*)(Rb + o0.w);                          \
    T[4]  = *(const half8_t*)(Rb + o1.x);                          \
    T[5]  = *(const half8_t*)(Rb + o1.y);                          \
    T[6]  = *(const half8_t*)(Rb + o1.z);                          \
    T[7]  = *(const half8_t*)(Rb + o1.w);                          \
    T[8]  = *(const half8_t*)(Rb + o2.x);                          \
    T[9]  = *(const half8_t*)(Rb + o2.y);                          \
    T[10] = *(const half8_t*)(Rb + o2.z);                          \
    T[11] = *(const half8_t*)(Rb + o2.w);                          \
  } while (0)

#define COMP_TAPS(T, KB) do {                                      \
    _Pragma("unroll")                                              \
    for (int j = 0; j < 3; ++j) {                                  \
      float4 w4 = mp[(KB) + j].wgt;                                \
      float d00 = dot8(T[4 * j + 0], l8, 0.f);                     \
      float d01 = dot8(T[4 * j + 1], l8, 0.f);                     \
      float d10 = dot8(T[4 * j + 2], l8, 0.f);                     \
      float d11 = dot8(T[4 * j + 3], l8, 0.f);                     \
      float r = w4.x * d00 + w4.y * d01 + w4.z * d10 + w4.w * d11; \
      r += __shfl_xor(r, 1);                                       \
      r += __shfl_xor(r, 2);                                       \
      r += __shfl_xor(r, 4);                                       \
      rr[(KB) + j] = r;                                            \
    }                                                              \
  } while (0)

  // R20: hard scheduler fences -- nothing crosses sched_barrier(0).
  LOAD_TAPS(tA, 0);
  LOAD_TAPS(tB, 3);
  __builtin_amdgcn_sched_barrier(0);   // 24 taps now forced live
  COMP_TAPS(tA, 0);
  LOAD_TAPS(tA, 6);
  __builtin_amdgcn_sched_barrier(0);   // keep (A,6) issue ahead of C(B,3)
  COMP_TAPS(tB, 3);
  COMP_TAPS(tA, 6);

#undef LOAD_TAPS
#undef COMP_TAPS

  // single masked store block: exec mask changes once
  int g = cl >> 3;
  if ((cl & 7) == 0) {
    float* outp = out + ((size_t)b * kG + g) * kK * kHW + pix;
    #pragma unroll
    for (int k = 0; k < kK; ++k)
      outp[(size_t)k * kHW] = rr[k] * (1.f / kGC);
  }
}

// ---- fallback (round-2 kernel) if workspace too small ----
__global__ __launch_bounds__(256) void crestereo_corr_fallback(
    const float* __restrict__ left, const float* __restrict__ right,
    const float* __restrict__ flow, const float* __restrict__ extra,
    float* __restrict__ out)
{
  int t = blockIdx.x * blockDim.x + threadIdx.x;
  int w = t % kW;
  int h = (t / kW) % kH;
  int k = (t / kHW) % kK;
  int g = (t / (kHW * kK)) % kG;
  int b = t / (kHW * kK * kG);

  int pix = h * kW + w;
  const float* flowb = flow + b * 2 * kHW + pix;
  float x = (float)(w + (k - 4)) + flowb[0];
  float y = (float)h + flowb[kHW];
  const float* extb = extra + (size_t)(b * 2 * kK + 2 * k) * kHW + pix;
  x += extb[0];
  y += extb[kHW];

  float xf = floorf(x), yf = floorf(y);
  float fx = x - xf, fy = y - yf;
  int ix0 = (int)xf, iy0 = (int)yf;
  int ix1 = ix0 + 1, iy1 = iy0 + 1;
  bool vx0 = (ix0 >= 0) && (ix0 < kW);
  bool vx1 = (ix1 >= 0) && (ix1 < kW);
  bool vy0 = (iy0 >= 0) && (iy0 < kH);
  bool vy1 = (iy1 >= 0) && (iy1 < kH);
  int xc0 = min(max(ix0, 0), kW - 1);
  int xc1 = min(max(ix1, 0), kW - 1);
  int yc0 = min(max(iy0, 0), kH - 1);
  int yc1 = min(max(iy1, 0), kH - 1);
  float wx0 = 1.f - fx, wy0 = 1.f - fy;
  float w00 = wx0 * wy0 * ((vx0 && vy0) ? 1.f : 0.f);
  float w01 = fx  * wy0 * ((vx1 && vy0) ? 1.f : 0.f);
  float w10 = wx0 * fy  * ((vx0 && vy1) ? 1.f : 0.f);
  float w11 = fx  * fy  * ((vx1 && vy1) ? 1.f : 0.f);
  int idx = yc0 * kW + xc0;
  int dx  = xc1 - xc0;
  int dyw = (yc1 - yc0) * kW;

  const float* Rb = right + (size_t)(b * kC + g * kGC) * kHW + idx;
  const float* Lb = left  + (size_t)(b * kC + g * kGC) * kHW + pix;

  float acc = 0.f;
  #pragma unroll 4
  for (int c = 0; c < kGC; ++c) {
    const float* Rc = Rb + (size_t)c * kHW;
    float l   = Lb[(size_t)c * kHW];
    acc += l * (w00 * Rc[0] + w01 * Rc[dx] + w10 * Rc[dyw] + w11 * Rc[dx + dyw]);
  }
  out[(size_t)((b * kG + g) * kK + k) * kHW + pix] = acc * (1.f / kGC);
}

extern "C" void kernel_launch(void* const* d_in, const int* in_sizes, int n_in,
                              void* d_out, int out_size, void* d_ws, size_t ws_size,
                              hipStream_t stream) {
  const float* left  = (const float*)d_in[0];
  const float* right = (const float*)d_in[1];
  const float* flow  = (const float*)d_in[2];
  const float* extra = (const float*)d_in[3];
  float* out = (float*)d_out;

  size_t t_bytes = (size_t)kB * kPlane * sizeof(_Float16);   // 18.9 MB (right_t)
  if (ws_size >= t_bytes) {
    _Float16* right_t = (_Float16*)d_ws;

    prepass_kernel<<<kTransBlocks, 256, 0, stream>>>(right, right_t);
    corr_fp16_kernel<<<kCorrBlocks, 256, 0, stream>>>(
        right_t, left, flow, extra, out);
  } else {
    int total = kB * kG * kK * kH * kW;
    crestereo_corr_fallback<<<(total + 255) / 256, 256, 0, stream>>>(
        left, right, flow, extra, out);
  }
}

// Round 9
// 136.857 us; speedup vs baseline: 1.0175x; 1.0001x over previous
//
#include <hip/hip_runtime.h>

// CREStereo grouped correlation, round 21.
// R20 post-mortem: fences moved VGPR 32->60 (partial pipeline) but corr only
// 45.5->44.5. Byte-reduction x3 and MLP x1 all ~neutral. Remaining model:
// address/line-lookup traffic. Per 8px block: taps ~2450 lines (fundamental
// gather) + left 1024 lines (64-distinct-line instructions!) + stores 576 +
// flow 160. R21 compresses the non-tap part via 16-px blocks (512 thr):
//  - left: 4 lanes per 64B ch-row -> 16 lines/instr (was 64); ~300 lines/16px
//  - flow/extra rows = full 64B lines
//  - stores through 2.3KB LDS bounce -> 36 coalesced lines (was 576)
// Tap path / meta math / dot math / fences unchanged -> absmax bit-identical.
// Predict corr 44 -> 36-39, total -> 129-132. If neutral: line model dead.

namespace {
constexpr int kB = 2;
constexpr int kC = 256;
constexpr int kH = 96;
constexpr int kW = 192;
constexpr int kG = 4;
constexpr int kGC = kC / kG;              // 64
constexpr int kK = 9;
constexpr int kHW = kH * kW;              // 18432
constexpr size_t kPlane = (size_t)kC * kHW;
constexpr int kTransBlocks = (kHW / 64) * (kC / 64) * kB;       // 2304 (right only)
constexpr int kPx = 16;                                         // px per corr block
constexpr int kCorrBlocks  = kB * kHW / kPx;                    // 2304
}

typedef _Float16 half8_t __attribute__((ext_vector_type(8)));
typedef _Float16 half2_t __attribute__((ext_vector_type(2)));

struct TapMeta {        // 32 B: one (b,px,k) candidate
  int4   off;           // element offsets of 4 taps into right_t plane
  float4 wgt;           // bilinear weights (validity folded in)
};

__device__ __forceinline__ float dot8(half8_t a, half8_t b, float acc) {
#if __has_builtin(__builtin_amdgcn_fdot2)
  #pragma unroll
  for (int i = 0; i < 4; ++i) {
    half2_t a2 = {a[2 * i], a[2 * i + 1]};
    half2_t b2 = {b[2 * i], b[2 * i + 1]};
    acc = __builtin_amdgcn_fdot2(a2, b2, acc, false);
  }
#else
  #pragma unroll
  for (int i = 0; i < 8; ++i) acc += (float)a[i] * (float)b[i];
#endif
  return acc;
}

// ---- pre-pass: fp32->fp16 64x64 transpose of RIGHT only, 2304 blocks ----
__global__ __launch_bounds__(256) void prepass_kernel(
    const float* __restrict__ right, _Float16* __restrict__ right_t)
{
  __shared__ float tile[64][65];
  int tb = blockIdx.x;
  int pt = tb % (kHW / 64);         // pixel tile 0..287
  int ct = (tb / (kHW / 64)) % 4;   // channel tile 0..3
  int b  = tb / ((kHW / 64) * 4);   // batch
  int p0 = pt * 64, c0 = ct * 64;
  const float* inb = right + (size_t)b * kPlane;
  _Float16*   outb = right_t + (size_t)b * kPlane;
  int t = threadIdx.x;
  int cl = t >> 2;
  int q  = t & 3;
  #pragma unroll
  for (int i = 0; i < 4; ++i) {
    int j = q + 4 * i;
    float4 v = *(const float4*)(inb + (size_t)(c0 + cl) * kHW + p0 + 4 * j);
    tile[cl][4 * j + 0] = v.x;
    tile[cl][4 * j + 1] = v.y;
    tile[cl][4 * j + 2] = v.z;
    tile[cl][4 * j + 3] = v.w;
  }
  __syncthreads();
  int pl8 = t >> 3;                 // pixel 0..31 (+32*i)
  int c8  = t & 7;                  // channel octet
  #pragma unroll
  for (int i = 0; i < 2; ++i) {
    int px = pl8 + 32 * i;
    half8_t hv;
    #pragma unroll
    for (int j = 0; j < 8; ++j)
      hv[j] = (_Float16)tile[8 * c8 + j][px];
    *(half8_t*)(outb + (size_t)(p0 + px) * kC + c0 + 8 * c8) = hv;
  }
}

// ---- main: block = 16 px, 512 thr (8 waves); wave = 2 px x 32 lanes ----
// R21: coalesced left (16 lines/instr), LDS-bounced coalesced stores.
__global__ __launch_bounds__(512, 4) void corr_fp16_kernel(
    const _Float16* __restrict__ right_t, const float* __restrict__ left,
    const float* __restrict__ flow, const float* __restrict__ extra,
    float* __restrict__ out)
{
  __shared__ _Float16 smleft[kPx][kC];      // 8 KB
  __shared__ float    smflow[20][kPx];      // 1280 B: rows 0-1 flow, 2-19 extra
  __shared__ TapMeta  smeta[kPx * kK];      // 4608 B
  __shared__ float    smout[kG * kK][kPx];  // 2304 B

  // XCD-chunked swizzle: 2304 blocks -> XCD i owns blocks [i*288,(i+1)*288).
  int sb = (blockIdx.x & 7) * (kCorrBlocks / 8) + (blockIdx.x >> 3);
  int blockPix = sb * kPx;              // first of 16 pixels (global, b-major)
  int b    = blockPix / kHW;            // blocks never straddle batch
  int pix0 = blockPix % kHW;            // 16-aligned; 16|W -> same image row

  int t = threadIdx.x;

  // (1) left gather, coalesced: iter x (c = t>>2 + 128*it, q = t&3) loads
  //     float4 at row c, px 4q..4q+3 -> 4 consecutive lanes cover one 64B row.
  #pragma unroll
  for (int it = 0; it < 2; ++it) {
    int c = (t >> 2) + 128 * it;
    int q = t & 3;
    float4 v = *(const float4*)(left + (size_t)b * kPlane +
                                (size_t)c * kHW + pix0 + 4 * q);
    smleft[4 * q + 0][c] = (_Float16)v.x;
    smleft[4 * q + 1][c] = (_Float16)v.y;
    smleft[4 * q + 2][c] = (_Float16)v.z;
    smleft[4 * q + 3][c] = (_Float16)v.w;
  }

  // (2) flow/extra stage: t<320 loads one float; each row = one 64B line.
  if (t < 320) {
    int fr = t >> 4, fpx = t & 15;
    const float* src = (fr < 2)
        ? flow  + ((size_t)b * 2  + fr)       * kHW + pix0 + fpx
        : extra + ((size_t)b * 18 + (fr - 2)) * kHW + pix0 + fpx;
    smflow[fr][fpx] = *src;
  }
  __syncthreads();

  // (3) meta math from LDS: t<144 computes TapMeta for (px=t/9, k=t%9).
  if (t < kPx * kK) {
    int px = t / kK;
    int k  = t - px * kK;
    int gpix = pix0 + px;
    int w = gpix % kW, h = gpix / kW;

    float bx = (float)w + smflow[0][px];
    float by = (float)h + smflow[1][px];
    float xx = bx + (float)(k - 4) + smflow[2 + 2 * k][px];
    float yy = by + smflow[2 + 2 * k + 1][px];
    float xf = floorf(xx), yf = floorf(yy);
    float fx = xx - xf, fy = yy - yf;
    int ix0 = (int)xf, iy0 = (int)yf;
    int ix1 = ix0 + 1, iy1 = iy0 + 1;
    bool vx0 = (ix0 >= 0) && (ix0 < kW);
    bool vx1 = (ix1 >= 0) && (ix1 < kW);
    bool vy0 = (iy0 >= 0) && (iy0 < kH);
    bool vy1 = (iy1 >= 0) && (iy1 < kH);
    int xc0 = min(max(ix0, 0), kW - 1);
    int xc1 = min(max(ix1, 0), kW - 1);
    int yc0 = min(max(iy0, 0), kH - 1);
    int yc1 = min(max(iy1, 0), kH - 1);
    float wx0 = 1.f - fx, wy0 = 1.f - fy;
    TapMeta m;
    m.off.x = (yc0 * kW + xc0) * kC;
    m.off.y = (yc0 * kW + xc1) * kC;
    m.off.z = (yc1 * kW + xc0) * kC;
    m.off.w = (yc1 * kW + xc1) * kC;
    m.wgt.x = wx0 * wy0 * ((vx0 && vy0) ? 1.f : 0.f);
    m.wgt.y = fx  * wy0 * ((vx1 && vy0) ? 1.f : 0.f);
    m.wgt.z = wx0 * fy  * ((vx0 && vy1) ? 1.f : 0.f);
    m.wgt.w = fx  * fy  * ((vx1 && vy1) ? 1.f : 0.f);
    smeta[t] = m;
  }

  int wv   = t >> 6;                    // wave in block 0..7
  int lane = t & 63;
  int p    = lane >> 5;                 // pixel cluster 0..1
  int cl   = lane & 31;                 // channel-lane: owns channels cl*8..cl*8+7
  int px   = wv * 2 + p;                // block-local pixel 0..15

  const _Float16* Rb = right_t + (size_t)b * kPlane + cl * 8;

  __syncthreads();

  half8_t l8 = *(const half8_t*)&smleft[px][cl * 8];
  const TapMeta* mp = smeta + px * kK;  // LDS, broadcast reads

  float rr[kK];
  half8_t tA[12], tB[12];

#define LOAD_TAPS(T, KB) do {                                      \
    int4 o0 = mp[(KB)].off, o1 = mp[(KB) + 1].off, o2 = mp[(KB) + 2].off; \
    T[0]  = *(const half8_t*)(Rb + o0.x);                          \
    T[1]  = *(const half8_t*)(Rb + o0.y);                          \
    T[2]  = *(const half8_t*)(Rb + o0.z);                          \
    T[3]  = *(const half8_t*)(Rb + o0.w);                          \
    T[4]  = *(const half8_t*)(Rb + o1.x);                          \
    T[5]  = *(const half8_t*)(Rb + o1.y);                          \
    T[6]  = *(const half8_t*)(Rb + o1.z);                          \
    T[7]  = *(const half8_t*)(Rb + o1.w);                          \
    T[8]  = *(const half8_t*)(Rb + o2.x);                          \
    T[9]  = *(const half8_t*)(Rb + o2.y);                          \
    T[10] = *(const half8_t*)(Rb + o2.z);                          \
    T[11] = *(const half8_t*)(Rb + o2.w);                          \
  } while (0)

#define COMP_TAPS(T, KB) do {                                      \
    _Pragma("unroll")                                              \
    for (int j = 0; j < 3; ++j) {                                  \
      float4 w4 = mp[(KB) + j].wgt;                                \
      float d00 = dot8(T[4 * j + 0], l8, 0.f);                     \
      float d01 = dot8(T[4 * j + 1], l8, 0.f);                     \
      float d10 = dot8(T[4 * j + 2], l8, 0.f);                     \
      float d11 = dot8(T[4 * j + 3], l8, 0.f);                     \
      float r = w4.x * d00 + w4.y * d01 + w4.z * d10 + w4.w * d11; \
      r += __shfl_xor(r, 1);                                       \
      r += __shfl_xor(r, 2);                                       \
      r += __shfl_xor(r, 4);                                       \
      rr[(KB) + j] = r;                                            \
    }                                                              \
  } while (0)

  // sched_barrier-pinned 2-batch pipeline (R20)
  LOAD_TAPS(tA, 0);
  LOAD_TAPS(tB, 3);
  __builtin_amdgcn_sched_barrier(0);
  COMP_TAPS(tA, 0);
  LOAD_TAPS(tA, 6);
  __builtin_amdgcn_sched_barrier(0);
  COMP_TAPS(tB, 3);
  COMP_TAPS(tA, 6);

#undef LOAD_TAPS
#undef COMP_TAPS

  // (4) epilogue: bounce rr through LDS, then coalesced 64B-row stores.
  if ((cl & 7) == 0) {
    int g = cl >> 3;
    #pragma unroll
    for (int k = 0; k < kK; ++k)
      smout[g * kK + k][px] = rr[k] * (1.f / kGC);
  }
  __syncthreads();
  {
    float* ob = out + (size_t)b * kG * kK * kHW + pix0;
    int r   = t >> 4;          // 0..31
    int px2 = t & 15;
    ob[(size_t)r * kHW + px2] = smout[r][px2];
    if (t < (kG * kK - 32) * kPx) {       // rows 32..35
      int r2 = 32 + (t >> 4);
      ob[(size_t)r2 * kHW + px2] = smout[r2][px2];
    }
  }
}

// ---- fallback (round-2 kernel) if workspace too small ----
__global__ __launch_bounds__(256) void crestereo_corr_fallback(
    const float* __restrict__ left, const float* __restrict__ right,
    const float* __restrict__ flow, const float* __restrict__ extra,
    float* __restrict__ out)
{
  int t = blockIdx.x * blockDim.x + threadIdx.x;
  int w = t % kW;
  int h = (t / kW) % kH;
  int k = (t / kHW) % kK;
  int g = (t / (kHW * kK)) % kG;
  int b = t / (kHW * kK * kG);

  int pix = h * kW + w;
  const float* flowb = flow + b * 2 * kHW + pix;
  float x = (float)(w + (k - 4)) + flowb[0];
  float y = (float)h + flowb[kHW];
  const float* extb = extra + (size_t)(b * 2 * kK + 2 * k) * kHW + pix;
  x += extb[0];
  y += extb[kHW];

  float xf = floorf(x), yf = floorf(y);
  float fx = x - xf, fy = y - yf;
  int ix0 = (int)xf, iy0 = (int)yf;
  int ix1 = ix0 + 1, iy1 = iy0 + 1;
  bool vx0 = (ix0 >= 0) && (ix0 < kW);
  bool vx1 = (ix1 >= 0) && (ix1 < kW);
  bool vy0 = (iy0 >= 0) && (iy0 < kH);
  bool vy1 = (iy1 >= 0) && (iy1 < kH);
  int xc0 = min(max(ix0, 0), kW - 1);
  int xc1 = min(max(ix1, 0), kW - 1);
  int yc0 = min(max(iy0, 0), kH - 1);
  int yc1 = min(max(iy1, 0), kH - 1);
  float wx0 = 1.f - fx, wy0 = 1.f - fy;
  float w00 = wx0 * wy0 * ((vx0 && vy0) ? 1.f : 0.f);
  float w01 = fx  * wy0 * ((vx1 && vy0) ? 1.f : 0.f);
  float w10 = wx0 * fy  * ((vx0 && vy1) ? 1.f : 0.f);
  float w11 = fx  * fy  * ((vx1 && vy1) ? 1.f : 0.f);
  int idx = yc0 * kW + xc0;
  int dx  = xc1 - xc0;
  int dyw = (yc1 - yc0) * kW;

  const float* Rb = right + (size_t)(b * kC + g * kGC) * kHW + idx;
  const float* Lb = left  + (size_t)(b * kC + g * kGC) * kHW + pix;

  float acc = 0.f;
  #pragma unroll 4
  for (int c = 0; c < kGC; ++c) {
    const float* Rc = Rb + (size_t)c * kHW;
    float l   = Lb[(size_t)c * kHW];
    acc += l * (w00 * Rc[0] + w01 * Rc[dx] + w10 * Rc[dyw] + w11 * Rc[dx + dyw]);
  }
  out[(size_t)((b * kG + g) * kK + k) * kHW + pix] = acc * (1.f / kGC);
}

extern "C" void kernel_launch(void* const* d_in, const int* in_sizes, int n_in,
                              void* d_out, int out_size, void* d_ws, size_t ws_size,
                              hipStream_t stream) {
  const float* left  = (const float*)d_in[0];
  const float* right = (const float*)d_in[1];
  const float* flow  = (const float*)d_in[2];
  const float* extra = (const float*)d_in[3];
  float* out = (float*)d_out;

  size_t t_bytes = (size_t)kB * kPlane * sizeof(_Float16);   // 18.9 MB (right_t)
  if (ws_size >= t_bytes) {
    _Float16* right_t = (_Float16*)d_ws;

    prepass_kernel<<<kTransBlocks, 256, 0, stream>>>(right, right_t);
    corr_fp16_kernel<<<kCorrBlocks, 512, 0, stream>>>(
        right_t, left, flow, extra, out);
  } else {
    int total = kB * kG * kK * kH * kW;
    crestereo_corr_fallback<<<(total + 255) / 256, 256, 0, stream>>>(
        left, right, flow, extra, out);
  }
}

// Round 10
// 134.449 us; speedup vs baseline: 1.0357x; 1.0179x over previous
//
#include <hip/hip_runtime.h>

// CREStereo grouped correlation, round 22.
// R21 post-mortem: line-compression neutral (136.9 flat, corr ~43).
// Score: 4 byte/line-reduction attempts + 2 compiler-pipeline attempts, all
// ~neutral. Counters: no pipe >58% => exposed vmem latency. R19/R20 proved
// the COMPILER refuses a deep pipeline (VGPR stuck at 60 = ~10 loads in
// flight). R22: inline-asm counted-vmcnt pipeline (the AITER/HK mechanism):
//   issue 12(A)+12(B) asm global_load_dwordx4
//   s_waitcnt vmcnt(12) + sched_barrier(0)   <- rule-18 fence
//   comp A ; issue 12(C)
//   s_waitcnt vmcnt(12) + SB ; comp B
//   s_waitcnt vmcnt(0)  + SB ; comp C
// asm outputs can't be serialized away -> 24 dests forced live (~96 VGPR).
// VERIFY GATE: VGPR_Count >= 130 (else asm lost too). Predict corr 43->36-40,
// total ~130-134. absmax bit-identical. If VGPR jumps but corr flat ->
// structural floor, declare next round.

namespace {
constexpr int kB = 2;
constexpr int kC = 256;
constexpr int kH = 96;
constexpr int kW = 192;
constexpr int kG = 4;
constexpr int kGC = kC / kG;              // 64
constexpr int kK = 9;
constexpr int kHW = kH * kW;              // 18432
constexpr size_t kPlane = (size_t)kC * kHW;
constexpr int kTransBlocks = (kHW / 64) * (kC / 64) * kB;       // 2304 (right only)
constexpr int kPx = 16;                                         // px per corr block
constexpr int kCorrBlocks  = kB * kHW / kPx;                    // 2304
}

typedef _Float16 half8_t __attribute__((ext_vector_type(8)));
typedef _Float16 half2_t __attribute__((ext_vector_type(2)));

struct TapMeta {        // 32 B: one (b,px,k) candidate
  int4   off;           // element offsets of 4 taps into right_t plane
  float4 wgt;           // bilinear weights (validity folded in)
};

__device__ __forceinline__ float dot8(half8_t a, half8_t b, float acc) {
#if __has_builtin(__builtin_amdgcn_fdot2)
  #pragma unroll
  for (int i = 0; i < 4; ++i) {
    half2_t a2 = {a[2 * i], a[2 * i + 1]};
    half2_t b2 = {b[2 * i], b[2 * i + 1]};
    acc = __builtin_amdgcn_fdot2(a2, b2, acc, false);
  }
#else
  #pragma unroll
  for (int i = 0; i < 8; ++i) acc += (float)a[i] * (float)b[i];
#endif
  return acc;
}

// R22: raw 16B load -- compiler can't serialize/reschedule these; completion
// is managed by manual counted s_waitcnt below.
__device__ __forceinline__ half8_t ld16(const _Float16* p) {
  half8_t r;
  asm volatile("global_load_dwordx4 %0, %1, off"
               : "=&v"(r) : "v"(p));
  return r;
}

// ---- pre-pass: fp32->fp16 64x64 transpose of RIGHT only, 2304 blocks ----
__global__ __launch_bounds__(256) void prepass_kernel(
    const float* __restrict__ right, _Float16* __restrict__ right_t)
{
  __shared__ float tile[64][65];
  int tb = blockIdx.x;
  int pt = tb % (kHW / 64);         // pixel tile 0..287
  int ct = (tb / (kHW / 64)) % 4;   // channel tile 0..3
  int b  = tb / ((kHW / 64) * 4);   // batch
  int p0 = pt * 64, c0 = ct * 64;
  const float* inb = right + (size_t)b * kPlane;
  _Float16*   outb = right_t + (size_t)b * kPlane;
  int t = threadIdx.x;
  int cl = t >> 2;
  int q  = t & 3;
  #pragma unroll
  for (int i = 0; i < 4; ++i) {
    int j = q + 4 * i;
    float4 v = *(const float4*)(inb + (size_t)(c0 + cl) * kHW + p0 + 4 * j);
    tile[cl][4 * j + 0] = v.x;
    tile[cl][4 * j + 1] = v.y;
    tile[cl][4 * j + 2] = v.z;
    tile[cl][4 * j + 3] = v.w;
  }
  __syncthreads();
  int pl8 = t >> 3;                 // pixel 0..31 (+32*i)
  int c8  = t & 7;                  // channel octet
  #pragma unroll
  for (int i = 0; i < 2; ++i) {
    int px = pl8 + 32 * i;
    half8_t hv;
    #pragma unroll
    for (int j = 0; j < 8; ++j)
      hv[j] = (_Float16)tile[8 * c8 + j][px];
    *(half8_t*)(outb + (size_t)(p0 + px) * kC + c0 + 8 * c8) = hv;
  }
}

// ---- main: block = 16 px, 512 thr (8 waves); wave = 2 px x 32 lanes ----
// R22: asm counted-vmcnt 3-batch tap pipeline. Rest frozen at R21.
__global__ __launch_bounds__(512, 2) void corr_fp16_kernel(
    const _Float16* __restrict__ right_t, const float* __restrict__ left,
    const float* __restrict__ flow, const float* __restrict__ extra,
    float* __restrict__ out)
{
  __shared__ _Float16 smleft[kPx][kC];      // 8 KB
  __shared__ float    smflow[20][kPx];      // 1280 B: rows 0-1 flow, 2-19 extra
  __shared__ TapMeta  smeta[kPx * kK];      // 4608 B
  __shared__ float    smout[kG * kK][kPx];  // 2304 B

  // XCD-chunked swizzle: 2304 blocks -> XCD i owns blocks [i*288,(i+1)*288).
  int sb = (blockIdx.x & 7) * (kCorrBlocks / 8) + (blockIdx.x >> 3);
  int blockPix = sb * kPx;              // first of 16 pixels (global, b-major)
  int b    = blockPix / kHW;            // blocks never straddle batch
  int pix0 = blockPix % kHW;            // 16-aligned; 16|W -> same image row

  int t = threadIdx.x;

  // (1) left gather, coalesced: 4 consecutive lanes cover one 64B ch-row.
  #pragma unroll
  for (int it = 0; it < 2; ++it) {
    int c = (t >> 2) + 128 * it;
    int q = t & 3;
    float4 v = *(const float4*)(left + (size_t)b * kPlane +
                                (size_t)c * kHW + pix0 + 4 * q);
    smleft[4 * q + 0][c] = (_Float16)v.x;
    smleft[4 * q + 1][c] = (_Float16)v.y;
    smleft[4 * q + 2][c] = (_Float16)v.z;
    smleft[4 * q + 3][c] = (_Float16)v.w;
  }

  // (2) flow/extra stage: t<320 loads one float; each row = one 64B line.
  if (t < 320) {
    int fr = t >> 4, fpx = t & 15;
    const float* src = (fr < 2)
        ? flow  + ((size_t)b * 2  + fr)       * kHW + pix0 + fpx
        : extra + ((size_t)b * 18 + (fr - 2)) * kHW + pix0 + fpx;
    smflow[fr][fpx] = *src;
  }
  __syncthreads();

  // (3) meta math from LDS: t<144 computes TapMeta for (px=t/9, k=t%9).
  if (t < kPx * kK) {
    int px = t / kK;
    int k  = t - px * kK;
    int gpix = pix0 + px;
    int w = gpix % kW, h = gpix / kW;

    float bx = (float)w + smflow[0][px];
    float by = (float)h + smflow[1][px];
    float xx = bx + (float)(k - 4) + smflow[2 + 2 * k][px];
    float yy = by + smflow[2 + 2 * k + 1][px];
    float xf = floorf(xx), yf = floorf(yy);
    float fx = xx - xf, fy = yy - yf;
    int ix0 = (int)xf, iy0 = (int)yf;
    int ix1 = ix0 + 1, iy1 = iy0 + 1;
    bool vx0 = (ix0 >= 0) && (ix0 < kW);
    bool vx1 = (ix1 >= 0) && (ix1 < kW);
    bool vy0 = (iy0 >= 0) && (iy0 < kH);
    bool vy1 = (iy1 >= 0) && (iy1 < kH);
    int xc0 = min(max(ix0, 0), kW - 1);
    int xc1 = min(max(ix1, 0), kW - 1);
    int yc0 = min(max(iy0, 0), kH - 1);
    int yc1 = min(max(iy1, 0), kH - 1);
    float wx0 = 1.f - fx, wy0 = 1.f - fy;
    TapMeta m;
    m.off.x = (yc0 * kW + xc0) * kC;
    m.off.y = (yc0 * kW + xc1) * kC;
    m.off.z = (yc1 * kW + xc0) * kC;
    m.off.w = (yc1 * kW + xc1) * kC;
    m.wgt.x = wx0 * wy0 * ((vx0 && vy0) ? 1.f : 0.f);
    m.wgt.y = fx  * wy0 * ((vx1 && vy0) ? 1.f : 0.f);
    m.wgt.z = wx0 * fy  * ((vx0 && vy1) ? 1.f : 0.f);
    m.wgt.w = fx  * fy  * ((vx1 && vy1) ? 1.f : 0.f);
    smeta[t] = m;
  }

  int wv   = t >> 6;                    // wave in block 0..7
  int lane = t & 63;
  int p    = lane >> 5;                 // pixel cluster 0..1
  int cl   = lane & 31;                 // channel-lane: owns channels cl*8..cl*8+7
  int px   = wv * 2 + p;                // block-local pixel 0..15

  const _Float16* Rb = right_t + (size_t)b * kPlane + cl * 8;

  __syncthreads();                      // drains vmcnt/lgkmcnt -> clean slate

  half8_t l8 = *(const half8_t*)&smleft[px][cl * 8];
  const TapMeta* mp = smeta + px * kK;  // LDS, broadcast reads

  float rr[kK];
  half8_t tA[12], tB[12], tC[12];

#define ISSUE_TAPS(T, KB) do {                                           \
    int4 o0 = mp[(KB)].off, o1 = mp[(KB) + 1].off, o2 = mp[(KB) + 2].off; \
    T[0]  = ld16(Rb + o0.x);                                             \
    T[1]  = ld16(Rb + o0.y);                                             \
    T[2]  = ld16(Rb + o0.z);                                             \
    T[3]  = ld16(Rb + o0.w);                                             \
    T[4]  = ld16(Rb + o1.x);                                             \
    T[5]  = ld16(Rb + o1.y);                                             \
    T[6]  = ld16(Rb + o1.z);                                             \
    T[7]  = ld16(Rb + o1.w);                                             \
    T[8]  = ld16(Rb + o2.x);                                             \
    T[9]  = ld16(Rb + o2.y);                                             \
    T[10] = ld16(Rb + o2.z);                                             \
    T[11] = ld16(Rb + o2.w);                                             \
  } while (0)

#define COMP_TAPS(T, KB) do {                                      \
    _Pragma("unroll")                                              \
    for (int j = 0; j < 3; ++j) {                                  \
      float4 w4 = mp[(KB) + j].wgt;                                \
      float d00 = dot8(T[4 * j + 0], l8, 0.f);                     \
      float d01 = dot8(T[4 * j + 1], l8, 0.f);                     \
      float d10 = dot8(T[4 * j + 2], l8, 0.f);                     \
      float d11 = dot8(T[4 * j + 3], l8, 0.f);                     \
      float r = w4.x * d00 + w4.y * d01 + w4.z * d10 + w4.w * d11; \
      r += __shfl_xor(r, 1);                                       \
      r += __shfl_xor(r, 2);                                       \
      r += __shfl_xor(r, 4);                                       \
      rr[(KB) + j] = r;                                            \
    }                                                              \
  } while (0)

  // counted-vmcnt 3-batch pipeline (24 loads in flight at peak)
  ISSUE_TAPS(tA, 0);                              // vmcnt: 12
  ISSUE_TAPS(tB, 3);                              // vmcnt: 24
  asm volatile("s_waitcnt vmcnt(12)" ::: "memory");   // A complete
  __builtin_amdgcn_sched_barrier(0);
  COMP_TAPS(tA, 0);
  ISSUE_TAPS(tC, 6);                              // vmcnt: 24
  asm volatile("s_waitcnt vmcnt(12)" ::: "memory");   // B complete
  __builtin_amdgcn_sched_barrier(0);
  COMP_TAPS(tB, 3);
  asm volatile("s_waitcnt vmcnt(0)" ::: "memory");    // C complete
  __builtin_amdgcn_sched_barrier(0);
  COMP_TAPS(tC, 6);

#undef ISSUE_TAPS
#undef COMP_TAPS

  // (4) epilogue: bounce rr through LDS, then coalesced 64B-row stores.
  if ((cl & 7) == 0) {
    int g = cl >> 3;
    #pragma unroll
    for (int k = 0; k < kK; ++k)
      smout[g * kK + k][px] = rr[k] * (1.f / kGC);
  }
  __syncthreads();
  {
    float* ob = out + (size_t)b * kG * kK * kHW + pix0;
    int r   = t >> 4;          // 0..31
    int px2 = t & 15;
    ob[(size_t)r * kHW + px2] = smout[r][px2];
    if (t < (kG * kK - 32) * kPx) {       // rows 32..35
      int r2 = 32 + (t >> 4);
      ob[(size_t)r2 * kHW + px2] = smout[r2][px2];
    }
  }
}

// ---- fallback (round-2 kernel) if workspace too small ----
__global__ __launch_bounds__(256) void crestereo_corr_fallback(
    const float* __restrict__ left, const float* __restrict__ right,
    const float* __restrict__ flow, const float* __restrict__ extra,
    float* __restrict__ out)
{
  int t = blockIdx.x * blockDim.x + threadIdx.x;
  int w = t % kW;
  int h = (t / kW) % kH;
  int k = (t / kHW) % kK;
  int g = (t / (kHW * kK)) % kG;
  int b = t / (kHW * kK * kG);

  int pix = h * kW + w;
  const float* flowb = flow + b * 2 * kHW + pix;
  float x = (float)(w + (k - 4)) + flowb[0];
  float y = (float)h + flowb[kHW];
  const float* extb = extra + (size_t)(b * 2 * kK + 2 * k) * kHW + pix;
  x += extb[0];
  y += extb[kHW];

  float xf = floorf(x), yf = floorf(y);
  float fx = x - xf, fy = y - yf;
  int ix0 = (int)xf, iy0 = (int)yf;
  int ix1 = ix0 + 1, iy1 = iy0 + 1;
  bool vx0 = (ix0 >= 0) && (ix0 < kW);
  bool vx1 = (ix1 >= 0) && (ix1 < kW);
  bool vy0 = (iy0 >= 0) && (iy0 < kH);
  bool vy1 = (iy1 >= 0) && (iy1 < kH);
  int xc0 = min(max(ix0, 0), kW - 1);
  int xc1 = min(max(ix1, 0), kW - 1);
  int yc0 = min(max(iy0, 0), kH - 1);
  int yc1 = min(max(iy1, 0), kH - 1);
  float wx0 = 1.f - fx, wy0 = 1.f - fy;
  float w00 = wx0 * wy0 * ((vx0 && vy0) ? 1.f : 0.f);
  float w01 = fx  * wy0 * ((vx1 && vy0) ? 1.f : 0.f);
  float w10 = wx0 * fy  * ((vx0 && vy1) ? 1.f : 0.f);
  float w11 = fx  * fy  * ((vx1 && vy1) ? 1.f : 0.f);
  int idx = yc0 * kW + xc0;
  int dx  = xc1 - xc0;
  int dyw = (yc1 - yc0) * kW;

  const float* Rb = right + (size_t)(b * kC + g * kGC) * kHW + idx;
  const float* Lb = left  + (size_t)(b * kC + g * kGC) * kHW + pix;

  float acc = 0.f;
  #pragma unroll 4
  for (int c = 0; c < kGC; ++c) {
    const float* Rc = Rb + (size_t)c * kHW;
    float l   = Lb[(size_t)c * kHW];
    acc += l * (w00 * Rc[0] + w01 * Rc[dx] + w10 * Rc[dyw] + w11 * Rc[dx + dyw]);
  }
  out[(size_t)((b * kG + g) * kK + k) * kHW + pix] = acc * (1.f / kGC);
}

extern "C" void kernel_launch(void* const* d_in, const int* in_sizes, int n_in,
                              void* d_out, int out_size, void* d_ws, size_t ws_size,
                              hipStream_t stream) {
  const float* left  = (const float*)d_in[0];
  const float* right = (const float*)d_in[1];
  const float* flow  = (const float*)d_in[2];
  const float* extra = (const float*)d_in[3];
  float* out = (float*)d_out;

  size_t t_bytes = (size_t)kB * kPlane * sizeof(_Float16);   // 18.9 MB (right_t)
  if (ws_size >= t_bytes) {
    _Float16* right_t = (_Float16*)d_ws;

    prepass_kernel<<<kTransBlocks, 256, 0, stream>>>(right, right_t);
    corr_fp16_kernel<<<kCorrBlocks, 512, 0, stream>>>(
        right_t, left, flow, extra, out);
  } else {
    int total = kB * kG * kK * kH * kW;
    crestereo_corr_fallback<<<(total + 255) / 256, 256, 0, stream>>>(
        left, right, flow, extra, out);
  }
}